// Round 6
// baseline (324.069 us; speedup 1.0000x reference)
//
#include <hip/hip_runtime.h>

// Flash-style fused attention, f16 MFMA (16x16x32), no-max softmax, split-K=2.
// B=16, S=4096, D=64. Grid = 512 blocks (16b x 16 qt x 2 key-halves), 4 waves.
// BQ=256 (64 q-rows/wave). sK/sV: stride-64 (zero pad) + 16B-granule XOR
// swizzle g' = g ^ ((row>>1)&7) -> all staging writes and fragment reads at
// theoretical-min LDS cycles (kills the 8-way V-staging-write conflict).
// sV double-buffered: PV(t) MFMAs overlap staging writes of tile t+1.

#define NBATCH 16
#define SEQ    4096
#define DIM    64
#define BQ     256
#define BK     64
#define NKT    (SEQ / BK)
#define KHALF  (NKT / 2)
#define PSTR   72
#define OELEMS (NBATCH * SEQ * DIM)
#define NROWS  (NBATCH * SEQ)

#define QSCALE 0.180336879f   // 0.125 * log2(e)

typedef _Float16 half4_t __attribute__((ext_vector_type(4)));
typedef _Float16 half8_t __attribute__((ext_vector_type(8)));
typedef float    floatx4 __attribute__((ext_vector_type(4)));

__device__ inline float fast_exp2(float x) {
#if __has_builtin(__builtin_amdgcn_exp2f)
  return __builtin_amdgcn_exp2f(x);
#else
  return exp2f(x);
#endif
}
__device__ inline float fast_rcp(float x) {
#if __has_builtin(__builtin_amdgcn_rcpf)
  return __builtin_amdgcn_rcpf(x);
#else
  return 1.0f / x;
#endif
}

// swizzled offset in halfs for element (row, col) of a 64x64 half tile:
// granule g = col>>3 (16B), g' = g ^ ((row>>1)&7), offset o = col&7
__device__ inline int swz(int row, int col) {
  return row * 64 + ((((col >> 3) ^ ((row >> 1) & 7)) << 3) | (col & 7));
}

__global__ __launch_bounds__(256, 2)
void attn_f16_flash(const float* __restrict__ Qg, const float* __restrict__ Kg,
                    const float* __restrict__ Vg, float* __restrict__ O0g,
                    float* __restrict__ O1g, float* __restrict__ lsg)
{
  __shared__ __align__(16) _Float16 sK[64 * 64];         // [key][dim], swizzled
  __shared__ __align__(16) _Float16 sV[2][64 * 64];      // [dim][col'], swizzled
  __shared__ __align__(16) _Float16 sP[4 * 64 * PSTR];   // per-wave [row][col']

  const int tid  = threadIdx.x;
  const int wave = tid >> 6;
  const int lane = tid & 63;
  const int l16  = lane & 15;
  const int quad = lane >> 4;
  const int hK   = (l16 >> 1) & 7;   // read-swizzle key for all frag reads

  // staging decomposition: 16 threads x 4 dims per key-row, 16 key-groups
  const int t16 = tid & 15;          // dim quad index
  const int kg  = tid >> 4;          // key group 0..15

  const int bid  = blockIdx.x;
  const int half = bid & 1;
  const int qb   = bid >> 1;
  const int b    = qb >> 4;
  const int qt   = qb & 15;
  const int q0   = qt * BQ + wave * 64;
  const int kt0  = half * KHALF;

  const float* Qb = Qg + ((size_t)b * SEQ + q0) * DIM;
  const float* Kb = Kg + (size_t)b * SEQ * DIM;
  const float* Vb = Vg + (size_t)b * SEQ * DIM;
  float*       Ob = (half ? O1g : O0g) + ((size_t)b * SEQ + q0) * DIM;
  float*       Ls = lsg + half * NROWS + b * SEQ + q0;

  // ---- Q A-fragments, pre-scaled by 0.125*log2(e) ----
  half8_t qf[4][2];
  #pragma unroll
  for (int s = 0; s < 4; ++s)
    #pragma unroll
    for (int c = 0; c < 2; ++c) {
      const floatx4 f0 = *(const floatx4*)(Qb + (s * 16 + l16) * DIM + c * 32 + quad * 8);
      const floatx4 f1 = *(const floatx4*)(Qb + (s * 16 + l16) * DIM + c * 32 + quad * 8 + 4);
      half8_t h;
      #pragma unroll
      for (int j = 0; j < 4; ++j) h[j] = (_Float16)(f0[j] * QSCALE);
      #pragma unroll
      for (int j = 0; j < 4; ++j) h[4 + j] = (_Float16)(f1[j] * QSCALE);
      qf[s][c] = h;
    }

  floatx4 oacc[4][4];
  float   lsum[4][4];
  #pragma unroll
  for (int s = 0; s < 4; ++s) {
    #pragma unroll
    for (int n = 0; n < 4; ++n) oacc[s][n] = (floatx4){0.f, 0.f, 0.f, 0.f};
    #pragma unroll
    for (int r = 0; r < 4; ++r) lsum[s][r] = 0.f;
  }

  _Float16* myP = &sP[wave * 64 * PSTR];

  floatx4 kbuf[4], vbuf[4];

  // ---- load K/V tile kt into registers (float4, coalesced) ----
  #define LOAD_TILE(KT)                                                        \
    do {                                                                       \
      const float* Kt_ = Kb + (size_t)(KT) * BK * DIM;                         \
      const float* Vt_ = Vb + (size_t)(KT) * BK * DIM;                         \
      _Pragma("unroll")                                                        \
      for (int i = 0; i < 4; ++i) {                                            \
        const int key = kg + 16 * i;                                           \
        kbuf[i] = *(const floatx4*)(Kt_ + key * DIM + t16 * 4);                \
        vbuf[i] = *(const floatx4*)(Vt_ + key * DIM + t16 * 4);                \
      }                                                                        \
    } while (0)

  // ---- cvt + swizzled LDS writes; V transposed+permuted (col' = (k&15)*4 + k>>4)
  #define WRITE_TILE(VBUF)                                                     \
    do {                                                                       \
      _Pragma("unroll")                                                        \
      for (int i = 0; i < 4; ++i) {        /* K: row=key, col=t16*4..+3 */     \
        const int key = kg + 16 * i;                                           \
        half4_t h;                                                             \
        _Pragma("unroll")                                                      \
        for (int j = 0; j < 4; ++j) h[j] = (_Float16)kbuf[i][j];               \
        *(half4_t*)&sK[swz(key, t16 * 4)] = h;                                 \
      }                                                                        \
      _Pragma("unroll")                                                        \
      for (int e = 0; e < 4; ++e) {        /* V: row=dim, col'=kg*4..+3 */     \
        const int dim = t16 * 4 + e;                                           \
        half4_t h;                                                             \
        _Pragma("unroll")                                                      \
        for (int i = 0; i < 4; ++i) h[i] = (_Float16)vbuf[i][e];               \
        *(half4_t*)&(VBUF)[swz(dim, kg * 4)] = h;                              \
      }                                                                        \
    } while (0)

  #define QK_EXP()                                                             \
    do {                                                                       \
      floatx4 sc[4][4];                                                        \
      _Pragma("unroll")                                                        \
      for (int s = 0; s < 4; ++s)                                              \
        _Pragma("unroll")                                                      \
        for (int n = 0; n < 4; ++n) sc[s][n] = (floatx4){0.f, 0.f, 0.f, 0.f};  \
      _Pragma("unroll")                                                        \
      for (int n = 0; n < 4; ++n)                                              \
        _Pragma("unroll")                                                      \
        for (int c = 0; c < 2; ++c) {                                          \
          half8_t bf = *(const half8_t*)&sK[(n * 16 + l16) * 64 +              \
                                            (((c * 4 + quad) ^ hK) << 3)];     \
          _Pragma("unroll")                                                    \
          for (int s = 0; s < 4; ++s)                                          \
            sc[s][n] = __builtin_amdgcn_mfma_f32_16x16x32_f16(qf[s][c], bf,    \
                                                              sc[s][n], 0, 0, 0);\
        }                                                                      \
      _Pragma("unroll")                                                        \
      for (int s = 0; s < 4; ++s)                                              \
        _Pragma("unroll")                                                      \
        for (int r = 0; r < 4; ++r) {                                          \
          half4_t ph;                                                          \
          _Pragma("unroll")                                                    \
          for (int n = 0; n < 4; ++n) {                                        \
            float p = fast_exp2(sc[s][n][r]);                                  \
            lsum[s][r] += p;                                                   \
            ph[n] = (_Float16)p;                                               \
          }                                                                    \
          *(half4_t*)&myP[(s * 16 + quad * 4 + r) * PSTR + l16 * 4] = ph;      \
        }                                                                      \
    } while (0)

  #define PV(VBUF)                                                             \
    do {                                                                       \
      _Pragma("unroll")                                                        \
      for (int c = 0; c < 2; ++c) {                                            \
        half8_t pf[4];                                                         \
        _Pragma("unroll")                                                      \
        for (int s = 0; s < 4; ++s)                                            \
          pf[s] = *(const half8_t*)&myP[(s * 16 + l16) * PSTR + c * 32 + quad * 8];\
        _Pragma("unroll")                                                      \
        for (int n = 0; n < 4; ++n) {                                          \
          half8_t vf = *(const half8_t*)&(VBUF)[(n * 16 + l16) * 64 +          \
                                                (((c * 4 + quad) ^ hK) << 3)]; \
          _Pragma("unroll")                                                    \
          for (int s = 0; s < 4; ++s)                                          \
            oacc[s][n] = __builtin_amdgcn_mfma_f32_16x16x32_f16(pf[s], vf,     \
                                                                oacc[s][n], 0, 0, 0);\
        }                                                                      \
      }                                                                        \
    } while (0)

  // ---------- pipelined main loop ----------
  LOAD_TILE(kt0);
  WRITE_TILE(sV[0]);
  __syncthreads();
  int vb = 0;

  #pragma unroll 1
  for (int kt = kt0; kt < kt0 + KHALF - 1; ++kt) {
    LOAD_TILE(kt + 1);          // global loads in flight across compute
    QK_EXP();
    __syncthreads();            // all waves done reading sK(t)
    if (vb == 0) {
      WRITE_TILE(sV[1]);
      PV(sV[0]);
    } else {
      WRITE_TILE(sV[0]);
      PV(sV[1]);
    }
    __syncthreads();            // tile t+1 staged
    vb ^= 1;
  }
  QK_EXP();
  if (vb == 0) {
    PV(sV[0]);
  } else {
    PV(sV[1]);
  }

  // ---------- epilogue: UNNORMALIZED partial O + row sums ----------
  #pragma unroll
  for (int s = 0; s < 4; ++s) {
    float rsum[4];
    #pragma unroll
    for (int r = 0; r < 4; ++r) {
      float v = lsum[s][r];
      v += __shfl_xor(v, 1);
      v += __shfl_xor(v, 2);
      v += __shfl_xor(v, 4);
      v += __shfl_xor(v, 8);
      rsum[r] = v;
    }
    if (l16 == 0) {
      #pragma unroll
      for (int r = 0; r < 4; ++r)
        Ls[s * 16 + quad * 4 + r] = rsum[r];
    }
    #pragma unroll
    for (int n = 0; n < 4; ++n)
      #pragma unroll
      for (int r = 0; r < 4; ++r)
        Ob[(s * 16 + quad * 4 + r) * DIM + n * 16 + l16] = oacc[s][n][r];
  }
  #undef LOAD_TILE
  #undef WRITE_TILE
  #undef QK_EXP
  #undef PV
}

// O = (O0 + O1) / (l0 + l1); O0 in d_out (in-place), O1/l0/l1 in ws.
__global__ __launch_bounds__(256)
void attn_combine(float* __restrict__ O, const float* __restrict__ O1,
                  const float* __restrict__ lsg)
{
  const int i = blockIdx.x * 256 + threadIdx.x;   // float4 index
  const float* l0 = lsg;
  const float* l1 = lsg + NROWS;
  const int row = i >> 4;
  const float inv = fast_rcp(l0[row] + l1[row]);
  const float4 a  = ((const float4*)O)[i];
  const float4 bb = ((const float4*)O1)[i];
  float4 r;
  r.x = (a.x + bb.x) * inv;
  r.y = (a.y + bb.y) * inv;
  r.z = (a.z + bb.z) * inv;
  r.w = (a.w + bb.w) * inv;
  ((float4*)O)[i] = r;
}

extern "C" void kernel_launch(void* const* d_in, const int* in_sizes, int n_in,
                              void* d_out, int out_size, void* d_ws, size_t ws_size,
                              hipStream_t stream) {
  const float* Q = (const float*)d_in[0];
  const float* K = (const float*)d_in[1];
  const float* V = (const float*)d_in[2];
  float* O  = (float*)d_out;
  float* O1 = (float*)d_ws;
  float* Ls = (float*)d_ws + OELEMS;
  (void)in_sizes; (void)n_in; (void)out_size; (void)ws_size;

  attn_f16_flash<<<dim3(2 * NBATCH * (SEQ / BQ)), dim3(256), 0, stream>>>(Q, K, V, O, O1, Ls);
  attn_combine<<<dim3(OELEMS / 4 / 256), dim3(256), 0, stream>>>(O, O1, Ls);
}

// Round 7
// 190.502 us; speedup vs baseline: 1.7011x; 1.7011x over previous
//
#include <hip/hip_runtime.h>

// Flash-style fused attention, f16 MFMA (16x16x32), no-max softmax, split-K=2.
// B=16, S=4096, D=64. Grid = 512 blocks (16b x 16 qt x 2 key-halves), 4 waves.
// BQ=256 (64 q-rows/wave). All LDS tiles: stride-64 (zero pad) + 16B-granule
// XOR swizzle g' = g ^ ((row>>1)&7) -> staging writes & fragment reads at
// theoretical-min LDS bank cycles (verified: R6 dropped conflicts 13.6M->5.2M).
// Single-buffered, Round-4 loop shape (R6's dbuf+branch-dup caused ~350MB of
// scratch spill traffic -- reverted).

#define NBATCH 16
#define SEQ    4096
#define DIM    64
#define BQ     256
#define BK     64
#define NKT    (SEQ / BK)
#define KHALF  (NKT / 2)
#define OELEMS (NBATCH * SEQ * DIM)
#define NROWS  (NBATCH * SEQ)

#define QSCALE 0.180336879f   // 0.125 * log2(e)

typedef _Float16 half4_t __attribute__((ext_vector_type(4)));
typedef _Float16 half8_t __attribute__((ext_vector_type(8)));
typedef float    floatx4 __attribute__((ext_vector_type(4)));

__device__ inline float fast_exp2(float x) {
#if __has_builtin(__builtin_amdgcn_exp2f)
  return __builtin_amdgcn_exp2f(x);
#else
  return exp2f(x);
#endif
}
__device__ inline float fast_rcp(float x) {
#if __has_builtin(__builtin_amdgcn_rcpf)
  return __builtin_amdgcn_rcpf(x);
#else
  return 1.0f / x;
#endif
}

// swizzled offset in halfs for element (row, col) of a 64x64 half tile:
// granule g = col>>3 (16B), g' = g ^ ((row>>1)&7), offset o = col&7
__device__ inline int swz(int row, int col) {
  return row * 64 + ((((col >> 3) ^ ((row >> 1) & 7)) << 3) | (col & 7));
}

__global__ __launch_bounds__(256, 2)
void attn_f16_flash(const float* __restrict__ Qg, const float* __restrict__ Kg,
                    const float* __restrict__ Vg, float* __restrict__ O0g,
                    float* __restrict__ O1g, float* __restrict__ lsg)
{
  __shared__ __align__(16) _Float16 sK[64 * 64];        // [key][dim], swizzled
  __shared__ __align__(16) _Float16 sV[64 * 64];        // [dim][col'], swizzled
  __shared__ __align__(16) _Float16 sP[4 * 64 * 64];    // per-wave [row][col'], swizzled

  const int tid  = threadIdx.x;
  const int wave = tid >> 6;
  const int lane = tid & 63;
  const int l16  = lane & 15;
  const int quad = lane >> 4;
  const int hK   = (l16 >> 1) & 7;   // read-swizzle XOR key for frag reads

  // staging decomposition: 16 threads x 4 dims per key-row, 16 key-groups
  const int t16 = tid & 15;          // dim quad index
  const int kg  = tid >> 4;          // key group 0..15

  const int bid  = blockIdx.x;
  const int half = bid & 1;
  const int qb   = bid >> 1;
  const int b    = qb >> 4;
  const int qt   = qb & 15;
  const int q0   = qt * BQ + wave * 64;
  const int kt0  = half * KHALF;

  const float* Qb = Qg + ((size_t)b * SEQ + q0) * DIM;
  const float* Kb = Kg + (size_t)b * SEQ * DIM;
  const float* Vb = Vg + (size_t)b * SEQ * DIM;
  float*       Ob = (half ? O1g : O0g) + ((size_t)b * SEQ + q0) * DIM;
  float*       Ls = lsg + half * NROWS + b * SEQ + q0;

  // ---- Q A-fragments, pre-scaled by 0.125*log2(e) ----
  half8_t qf[4][2];
  #pragma unroll
  for (int s = 0; s < 4; ++s)
    #pragma unroll
    for (int c = 0; c < 2; ++c) {
      const floatx4 f0 = *(const floatx4*)(Qb + (s * 16 + l16) * DIM + c * 32 + quad * 8);
      const floatx4 f1 = *(const floatx4*)(Qb + (s * 16 + l16) * DIM + c * 32 + quad * 8 + 4);
      half8_t h;
      #pragma unroll
      for (int j = 0; j < 4; ++j) h[j] = (_Float16)(f0[j] * QSCALE);
      #pragma unroll
      for (int j = 0; j < 4; ++j) h[4 + j] = (_Float16)(f1[j] * QSCALE);
      qf[s][c] = h;
    }

  floatx4 oacc[4][4];
  float   lsum[4][4];
  #pragma unroll
  for (int s = 0; s < 4; ++s) {
    #pragma unroll
    for (int n = 0; n < 4; ++n) oacc[s][n] = (floatx4){0.f, 0.f, 0.f, 0.f};
    #pragma unroll
    for (int r = 0; r < 4; ++r) lsum[s][r] = 0.f;
  }

  _Float16* myP = &sP[wave * 64 * 64];

  floatx4 kbuf[4], vbuf[4];

  // ---- load K/V tile kt into registers (float4, coalesced) ----
  #define LOAD_TILE(KT)                                                        \
    do {                                                                       \
      const float* Kt_ = Kb + (size_t)(KT) * BK * DIM;                         \
      const float* Vt_ = Vb + (size_t)(KT) * BK * DIM;                         \
      _Pragma("unroll")                                                        \
      for (int i = 0; i < 4; ++i) {                                            \
        const int key = kg + 16 * i;                                           \
        kbuf[i] = *(const floatx4*)(Kt_ + key * DIM + t16 * 4);                \
        vbuf[i] = *(const floatx4*)(Vt_ + key * DIM + t16 * 4);                \
      }                                                                        \
    } while (0)

  // ---- cvt + swizzled LDS writes; V transposed+permuted (col' = (k&15)*4 + k>>4)
  #define WRITE_TILE()                                                         \
    do {                                                                       \
      _Pragma("unroll")                                                        \
      for (int i = 0; i < 4; ++i) {        /* K: row=key, col=t16*4..+3 */     \
        const int key = kg + 16 * i;                                           \
        half4_t h;                                                             \
        _Pragma("unroll")                                                      \
        for (int j = 0; j < 4; ++j) h[j] = (_Float16)kbuf[i][j];               \
        *(half4_t*)&sK[swz(key, t16 * 4)] = h;                                 \
      }                                                                        \
      _Pragma("unroll")                                                        \
      for (int e = 0; e < 4; ++e) {        /* V: row=dim, col'=kg*4..+3 */     \
        const int dim = t16 * 4 + e;                                           \
        half4_t h;                                                             \
        _Pragma("unroll")                                                      \
        for (int i = 0; i < 4; ++i) h[i] = (_Float16)vbuf[i][e];               \
        *(half4_t*)&sV[swz(dim, kg * 4)] = h;                                  \
      }                                                                        \
    } while (0)

  #define QK_EXP()                                                             \
    do {                                                                       \
      floatx4 sc[4][4];                                                        \
      _Pragma("unroll")                                                        \
      for (int s = 0; s < 4; ++s)                                              \
        _Pragma("unroll")                                                      \
        for (int n = 0; n < 4; ++n) sc[s][n] = (floatx4){0.f, 0.f, 0.f, 0.f};  \
      _Pragma("unroll")                                                        \
      for (int n = 0; n < 4; ++n)                                              \
        _Pragma("unroll")                                                      \
        for (int c = 0; c < 2; ++c) {                                          \
          half8_t bf = *(const half8_t*)&sK[(n * 16 + l16) * 64 +              \
                                            (((c * 4 + quad) ^ hK) << 3)];     \
          _Pragma("unroll")                                                    \
          for (int s = 0; s < 4; ++s)                                          \
            sc[s][n] = __builtin_amdgcn_mfma_f32_16x16x32_f16(qf[s][c], bf,    \
                                                              sc[s][n], 0, 0, 0);\
        }                                                                      \
      _Pragma("unroll")                                                        \
      for (int s = 0; s < 4; ++s)                                              \
        _Pragma("unroll")                                                      \
        for (int r = 0; r < 4; ++r) {                                          \
          const int prow = s * 16 + quad * 4 + r;                              \
          half4_t ph;                                                          \
          _Pragma("unroll")                                                    \
          for (int n = 0; n < 4; ++n) {                                        \
            float p = fast_exp2(sc[s][n][r]);                                  \
            lsum[s][r] += p;                                                   \
            ph[n] = (_Float16)p;                                               \
          }                                                                    \
          *(half4_t*)&myP[swz(prow, l16 * 4)] = ph;                            \
        }                                                                      \
    } while (0)

  #define PV()                                                                 \
    do {                                                                       \
      _Pragma("unroll")                                                        \
      for (int c = 0; c < 2; ++c) {                                            \
        half8_t pf[4];                                                         \
        _Pragma("unroll")                                                      \
        for (int s = 0; s < 4; ++s)                                            \
          pf[s] = *(const half8_t*)&myP[(s * 16 + l16) * 64 +                  \
                                        (((c * 4 + quad) ^ hK) << 3)];         \
        _Pragma("unroll")                                                      \
        for (int n = 0; n < 4; ++n) {                                          \
          half8_t vf = *(const half8_t*)&sV[(n * 16 + l16) * 64 +              \
                                            (((c * 4 + quad) ^ hK) << 3)];     \
          _Pragma("unroll")                                                    \
          for (int s = 0; s < 4; ++s)                                          \
            oacc[s][n] = __builtin_amdgcn_mfma_f32_16x16x32_f16(pf[s], vf,     \
                                                                oacc[s][n], 0, 0, 0);\
        }                                                                      \
      }                                                                        \
    } while (0)

  // ---------- pipelined main loop (Round-4 shape) ----------
  LOAD_TILE(kt0);
  WRITE_TILE();
  __syncthreads();

  #pragma unroll 1
  for (int kt = kt0; kt < kt0 + KHALF - 1; ++kt) {
    LOAD_TILE(kt + 1);          // global loads in flight across compute
    QK_EXP();
    PV();                       // sP is wave-private; sV(t) read pre-barrier
    __syncthreads();            // all waves done reading sK/sV(t)
    WRITE_TILE();
    __syncthreads();            // tile t+1 staged
  }
  QK_EXP();
  PV();

  // ---------- epilogue: UNNORMALIZED partial O + row sums ----------
  #pragma unroll
  for (int s = 0; s < 4; ++s) {
    float rsum[4];
    #pragma unroll
    for (int r = 0; r < 4; ++r) {
      float v = lsum[s][r];
      v += __shfl_xor(v, 1);
      v += __shfl_xor(v, 2);
      v += __shfl_xor(v, 4);
      v += __shfl_xor(v, 8);
      rsum[r] = v;
    }
    if (l16 == 0) {
      #pragma unroll
      for (int r = 0; r < 4; ++r)
        Ls[s * 16 + quad * 4 + r] = rsum[r];
    }
    #pragma unroll
    for (int n = 0; n < 4; ++n)
      #pragma unroll
      for (int r = 0; r < 4; ++r)
        Ob[(s * 16 + quad * 4 + r) * DIM + n * 16 + l16] = oacc[s][n][r];
  }
  #undef LOAD_TILE
  #undef WRITE_TILE
  #undef QK_EXP
  #undef PV
}

// O = (O0 + O1) / (l0 + l1); O0 in d_out (in-place), O1/l0/l1 in ws.
__global__ __launch_bounds__(256)
void attn_combine(float* __restrict__ O, const float* __restrict__ O1,
                  const float* __restrict__ lsg)
{
  const int i = blockIdx.x * 256 + threadIdx.x;   // float4 index
  const float* l0 = lsg;
  const float* l1 = lsg + NROWS;
  const int row = i >> 4;
  const float inv = fast_rcp(l0[row] + l1[row]);
  const float4 a  = ((const float4*)O)[i];
  const float4 bb = ((const float4*)O1)[i];
  float4 r;
  r.x = (a.x + bb.x) * inv;
  r.y = (a.y + bb.y) * inv;
  r.z = (a.z + bb.z) * inv;
  r.w = (a.w + bb.w) * inv;
  ((float4*)O)[i] = r;
}

extern "C" void kernel_launch(void* const* d_in, const int* in_sizes, int n_in,
                              void* d_out, int out_size, void* d_ws, size_t ws_size,
                              hipStream_t stream) {
  const float* Q = (const float*)d_in[0];
  const float* K = (const float*)d_in[1];
  const float* V = (const float*)d_in[2];
  float* O  = (float*)d_out;
  float* O1 = (float*)d_ws;
  float* Ls = (float*)d_ws + OELEMS;
  (void)in_sizes; (void)n_in; (void)out_size; (void)ws_size;

  attn_f16_flash<<<dim3(2 * NBATCH * (SEQ / BQ)), dim3(256), 0, stream>>>(Q, K, V, O, O1, Ls);
  attn_combine<<<dim3(OELEMS / 4 / 256), dim3(256), 0, stream>>>(O, O1, Ls);
}

// Round 8
// 168.417 us; speedup vs baseline: 1.9242x; 1.1311x over previous
//
#include <hip/hip_runtime.h>

// Transposed flash attention, f16 MFMA (16x16x32), no-max softmax, split-K=2.
// S^T = K*Q^T and O^T = V^T*P^T: for 16x16x32 f16 the A-frag and B-frag lane
// maps are identical, so Q frags serve as B unchanged, and S^T's C-layout puts
// KEYS in the lane-register dimension. Key order is free (PV contracts over
// keys), so choosing slot col' = (nk>>1)*32 + quad*8 + r*2 + (nk&1) makes the
// PV B-fragment an IN-LANE repack of the lane's own exp outputs:
//   bfrag(s,c)[j] = exp(sc[(c<<1)|(j&1)][s][j>>1])
// -> P never touches LDS. LDS = sK+sV = 16 KB. Denominator: 2 shuffles.
// Epilogue: 16 dwordx4 stores. Loop shape & barriers: Round-4 proven form.

#define NBATCH 16
#define SEQ    4096
#define DIM    64
#define BQ     256
#define BK     64
#define NKT    (SEQ / BK)
#define KHALF  (NKT / 2)
#define OELEMS (NBATCH * SEQ * DIM)
#define NROWS  (NBATCH * SEQ)

#define QSCALE 0.180336879f   // 0.125 * log2(e)

typedef _Float16 half2_t __attribute__((ext_vector_type(2)));
typedef _Float16 half4_t __attribute__((ext_vector_type(4)));
typedef _Float16 half8_t __attribute__((ext_vector_type(8)));
typedef float    floatx4 __attribute__((ext_vector_type(4)));

__device__ inline float fast_exp2(float x) {
#if __has_builtin(__builtin_amdgcn_exp2f)
  return __builtin_amdgcn_exp2f(x);
#else
  return exp2f(x);
#endif
}
__device__ inline float fast_rcp(float x) {
#if __has_builtin(__builtin_amdgcn_rcpf)
  return __builtin_amdgcn_rcpf(x);
#else
  return 1.0f / x;
#endif
}

// swizzled offset in halfs for element (row, col) of a 64x64 half tile:
// granule g = col>>3 (16B), g' = g ^ ((row>>1)&7), offset o = col&7
__device__ inline int swz(int row, int col) {
  return row * 64 + ((((col >> 3) ^ ((row >> 1) & 7)) << 3) | (col & 7));
}

__global__ __launch_bounds__(256, 2)
void attn_f16_flash(const float* __restrict__ Qg, const float* __restrict__ Kg,
                    const float* __restrict__ Vg, float* __restrict__ O0g,
                    float* __restrict__ O1g, float* __restrict__ lsg)
{
  __shared__ __align__(16) _Float16 sK[64 * 64];   // [key][dim], swizzled
  __shared__ __align__(16) _Float16 sV[64 * 64];   // [dim][slot], swizzled

  const int tid  = threadIdx.x;
  const int wave = tid >> 6;
  const int lane = tid & 63;
  const int l16  = lane & 15;
  const int quad = lane >> 4;
  const int hK   = (l16 >> 1) & 7;   // read-swizzle XOR key for frag reads

  // staging decomposition: t16 = dim-quad index, kg = key group 0..15
  const int t16 = tid & 15;
  const int kg  = tid >> 4;

  const int bid  = blockIdx.x;
  const int half = bid & 1;
  const int qb   = bid >> 1;
  const int b    = qb >> 4;
  const int qt   = qb & 15;
  const int q0   = qt * BQ + wave * 64;
  const int kt0  = half * KHALF;

  const float* Qb = Qg + ((size_t)b * SEQ + q0) * DIM;
  const float* Kb = Kg + (size_t)b * SEQ * DIM;
  const float* Vb = Vg + (size_t)b * SEQ * DIM;
  float*       Ob = (half ? O1g : O0g) + ((size_t)b * SEQ + q0) * DIM;
  float*       Ls = lsg + half * NROWS + b * SEQ + q0;

  // ---- Q fragments (B-operand of S^T = K*Q^T), pre-scaled by 0.125*log2(e)
  // B[k = quad*8+j (+32c)][n = l16] = Q[q = s*16+l16][dim = c*32+quad*8+j]
  half8_t qf[4][2];
  #pragma unroll
  for (int s = 0; s < 4; ++s)
    #pragma unroll
    for (int c = 0; c < 2; ++c) {
      const floatx4 f0 = *(const floatx4*)(Qb + (s * 16 + l16) * DIM + c * 32 + quad * 8);
      const floatx4 f1 = *(const floatx4*)(Qb + (s * 16 + l16) * DIM + c * 32 + quad * 8 + 4);
      half8_t h;
      #pragma unroll
      for (int j = 0; j < 4; ++j) h[j] = (_Float16)(f0[j] * QSCALE);
      #pragma unroll
      for (int j = 0; j < 4; ++j) h[4 + j] = (_Float16)(f1[j] * QSCALE);
      qf[s][c] = h;
    }

  floatx4 oacc2[4][4];   // [dim-tile n][q-slab s]: O^T[dim n*16+quad*4+r][q s*16+l16]
  float   lsum2[4];      // per-lane partial denominator for q = s*16+l16
  #pragma unroll
  for (int n = 0; n < 4; ++n)
    #pragma unroll
    for (int s = 0; s < 4; ++s) oacc2[n][s] = (floatx4){0.f, 0.f, 0.f, 0.f};
  #pragma unroll
  for (int s = 0; s < 4; ++s) lsum2[s] = 0.f;

  floatx4 kbuf[4], vbuf[4];

  // ---- load K/V tile kt into registers (float4, coalesced) ----
  #define LOAD_TILE(KT)                                                        \
    do {                                                                       \
      const float* Kt_ = Kb + (size_t)(KT) * BK * DIM;                         \
      const float* Vt_ = Vb + (size_t)(KT) * BK * DIM;                         \
      _Pragma("unroll")                                                        \
      for (int i = 0; i < 4; ++i) {                                            \
        const int key = kg + 16 * i;                                           \
        kbuf[i] = *(const floatx4*)(Kt_ + key * DIM + t16 * 4);                \
        vbuf[i] = *(const floatx4*)(Vt_ + key * DIM + t16 * 4);                \
      }                                                                        \
    } while (0)

  // K: [key][dim] swizzled, b64 writes.
  // V: [dim][slot] swizzled; key kg+16i -> slot (i>>1)*32 + (kg>>2)*8 +
  //    (kg&3)*2 + (i&1): i-pairs (0,1) and (2,3) are column-adjacent -> b32.
  #define WRITE_TILE()                                                         \
    do {                                                                       \
      _Pragma("unroll")                                                        \
      for (int i = 0; i < 4; ++i) {                                            \
        const int key = kg + 16 * i;                                           \
        half4_t h;                                                             \
        _Pragma("unroll")                                                      \
        for (int j = 0; j < 4; ++j) h[j] = (_Float16)kbuf[i][j];               \
        *(half4_t*)&sK[swz(key, t16 * 4)] = h;                                 \
      }                                                                        \
      {                                                                        \
        const int vbase = (kg >> 2) * 8 + (kg & 3) * 2;                        \
        _Pragma("unroll")                                                      \
        for (int e = 0; e < 4; ++e) {                                          \
          const int dim = t16 * 4 + e;                                         \
          half2_t h0; h0[0] = (_Float16)vbuf[0][e]; h0[1] = (_Float16)vbuf[1][e];\
          half2_t h1; h1[0] = (_Float16)vbuf[2][e]; h1[1] = (_Float16)vbuf[3][e];\
          *(half2_t*)&sV[swz(dim, vbase)]      = h0;                           \
          *(half2_t*)&sV[swz(dim, vbase + 32)] = h1;                           \
        }                                                                      \
      }                                                                        \
    } while (0)

  #define COMPUTE_TILE()                                                       \
    do {                                                                       \
      floatx4 sc[4][4];   /* [key-tile nk][q-slab s] */                        \
      _Pragma("unroll")                                                        \
      for (int nk = 0; nk < 4; ++nk)                                           \
        _Pragma("unroll")                                                      \
        for (int s = 0; s < 4; ++s) sc[nk][s] = (floatx4){0.f, 0.f, 0.f, 0.f}; \
      /* S^T = K * Q^T: A-frag from sK (key rows), B = qf */                   \
      _Pragma("unroll")                                                        \
      for (int nk = 0; nk < 4; ++nk)                                           \
        _Pragma("unroll")                                                      \
        for (int c = 0; c < 2; ++c) {                                          \
          half8_t kf = *(const half8_t*)&sK[(nk * 16 + l16) * 64 +             \
                                            (((c * 4 + quad) ^ hK) << 3)];     \
          _Pragma("unroll")                                                    \
          for (int s = 0; s < 4; ++s)                                          \
            sc[nk][s] = __builtin_amdgcn_mfma_f32_16x16x32_f16(kf, qf[s][c],   \
                                                               sc[nk][s], 0, 0, 0);\
        }                                                                      \
      /* exp + in-lane repack to PV B-frags + denominator accumulate */        \
      half8_t bfrag[4][2];                                                     \
      _Pragma("unroll")                                                        \
      for (int s = 0; s < 4; ++s)                                              \
        _Pragma("unroll")                                                      \
        for (int c = 0; c < 2; ++c) {                                          \
          half8_t bf;                                                          \
          _Pragma("unroll")                                                    \
          for (int j = 0; j < 8; ++j) {                                        \
            float p = fast_exp2(sc[(c << 1) | (j & 1)][s][j >> 1]);            \
            lsum2[s] += p;                                                     \
            bf[j] = (_Float16)p;                                               \
          }                                                                    \
          bfrag[s][c] = bf;                                                    \
        }                                                                      \
      /* O^T += V^T * P^T: A-frag from sV, B = bfrag (registers) */            \
      _Pragma("unroll")                                                        \
      for (int c = 0; c < 2; ++c)                                              \
        _Pragma("unroll")                                                      \
        for (int n = 0; n < 4; ++n) {                                          \
          half8_t vf = *(const half8_t*)&sV[(n * 16 + l16) * 64 +              \
                                            (((c * 4 + quad) ^ hK) << 3)];     \
          _Pragma("unroll")                                                    \
          for (int s = 0; s < 4; ++s)                                          \
            oacc2[n][s] = __builtin_amdgcn_mfma_f32_16x16x32_f16(vf, bfrag[s][c],\
                                                                 oacc2[n][s], 0, 0, 0);\
        }                                                                      \
    } while (0)

  // ---------- pipelined main loop over this block's key half ----------
  LOAD_TILE(kt0);
  WRITE_TILE();
  __syncthreads();

  #pragma unroll 1
  for (int kt = kt0; kt < kt0 + KHALF - 1; ++kt) {
    LOAD_TILE(kt + 1);          // global loads in flight across compute
    COMPUTE_TILE();
    __syncthreads();            // all waves done reading sK/sV(t)
    WRITE_TILE();
    __syncthreads();            // tile t+1 staged
  }
  COMPUTE_TILE();

  // ---------- epilogue: UNNORMALIZED partial O + row sums ----------
  #pragma unroll
  for (int s = 0; s < 4; ++s) {
    float v = lsum2[s];
    v += __shfl_xor(v, 16);
    v += __shfl_xor(v, 32);     // sum over all 64 keys-in-tile groups
    if (lane < 16) Ls[s * 16 + l16] = v;
  }
  #pragma unroll
  for (int s = 0; s < 4; ++s)
    #pragma unroll
    for (int n = 0; n < 4; ++n)
      *(floatx4*)&Ob[(s * 16 + l16) * DIM + n * 16 + quad * 4] = oacc2[n][s];

  #undef LOAD_TILE
  #undef WRITE_TILE
  #undef COMPUTE_TILE
}

// O = (O0 + O1) / (l0 + l1); O0 in d_out (in-place), O1/l0/l1 in ws.
__global__ __launch_bounds__(256)
void attn_combine(float* __restrict__ O, const float* __restrict__ O1,
                  const float* __restrict__ lsg)
{
  const int i = blockIdx.x * 256 + threadIdx.x;   // float4 index
  const float* l0 = lsg;
  const float* l1 = lsg + NROWS;
  const int row = i >> 4;
  const float inv = fast_rcp(l0[row] + l1[row]);
  const float4 a  = ((const float4*)O)[i];
  const float4 bb = ((const float4*)O1)[i];
  float4 r;
  r.x = (a.x + bb.x) * inv;
  r.y = (a.y + bb.y) * inv;
  r.z = (a.z + bb.z) * inv;
  r.w = (a.w + bb.w) * inv;
  ((float4*)O)[i] = r;
}

extern "C" void kernel_launch(void* const* d_in, const int* in_sizes, int n_in,
                              void* d_out, int out_size, void* d_ws, size_t ws_size,
                              hipStream_t stream) {
  const float* Q = (const float*)d_in[0];
  const float* K = (const float*)d_in[1];
  const float* V = (const float*)d_in[2];
  float* O  = (float*)d_out;
  float* O1 = (float*)d_ws;
  float* Ls = (float*)d_ws + OELEMS;
  (void)in_sizes; (void)n_in; (void)out_size; (void)ws_size;

  attn_f16_flash<<<dim3(2 * NBATCH * (SEQ / BQ)), dim3(256), 0, stream>>>(Q, K, V, O, O1, Ls);
  attn_combine<<<dim3(OELEMS / 4 / 256), dim3(256), 0, stream>>>(O, O1, Ls);
}